// Round 4
// baseline (212.209 us; speedup 1.0000x reference)
//
#include <hip/hip_runtime.h>
#include <math.h>

// Problem constants: C=256, H=W=128, PH=PW=8.
#define C_ 256
#define H_ 128
#define W_ 128
#define PH_ 8
#define PW_ 8

// One wave per (n, c). Block = 4 waves = one ROI, 4 consecutive channels.
// bid&7 -> XCD-affine 32-channel chunk (per-XCD fm footprint = 2 MB, L2-resident).
// Lane owns absolute columns 2*lane, 2*lane+1 of the plane row; loads are
// predicated to the ROI column range so L2 traffic ~ rW*4 B per row.
__global__ __launch_bounds__(256) void roi_pool_kernel(
    const float* __restrict__ fm,
    const int* __restrict__ rois,
    float* __restrict__ out,
    int N)
{
    const int wid  = threadIdx.x >> 6;
    const int lane = threadIdx.x & 63;

    const int bid  = blockIdx.x;
    const int xcd  = bid & 7;
    const int t    = bid >> 3;
    const int csub = t & 7;
    const int n    = t >> 3;
    if (n >= N) return;
    const int c = (xcd << 5) + (csub << 2) + wid;

    const int4 roi = ((const int4*)rois)[n];
    const int y = roi.x, x = roi.y, rH = roi.z, rW = roi.w;

    const float2* plane2 = (const float2*)(fm + (size_t)c * (H_ * W_));

    // Load predicate: lane covers cols {2l, 2l+1}; needed iff overlap with [x, x+rW).
    const int col0 = lane * 2;
    const bool active = (col0 + 1 >= x) && (col0 < x + rW);

    const int pw = lane & 7;
    const int j  = lane >> 3;
    const int ws = (pw * rW) >> 3;                  // floor(pw*rW/8)
    const int we = (((pw + 1) * rW) + 7) >> 3;      // ceil((pw+1)*rW/8)

    float keep = 0.0f;

    for (int ph = 0; ph < PH_; ++ph) {
        const int hs = (ph * rH) >> 3;
        const int he = ((ph + 1) * rH + 7) >> 3;

        float m0 = -INFINITY, m1 = -INFINITY;

        if (active) {
            const float2* p = plane2 + (size_t)(y + hs) * (W_ / 2) + lane;
            int cnt = he - hs;                       // wave-uniform
            while (cnt >= 4) {
                const float2 v0 = p[0 * (W_ / 2)];
                const float2 v1 = p[1 * (W_ / 2)];
                const float2 v2 = p[2 * (W_ / 2)];
                const float2 v3 = p[3 * (W_ / 2)];
                p += 4 * (W_ / 2);
                cnt -= 4;
                m0 = fmaxf(m0, fmaxf(fmaxf(v0.x, v1.x), fmaxf(v2.x, v3.x)));
                m1 = fmaxf(m1, fmaxf(fmaxf(v0.y, v1.y), fmaxf(v2.y, v3.y)));
            }
            while (cnt > 0) {
                const float2 v0 = p[0];
                p += (W_ / 2);
                --cnt;
                m0 = fmaxf(m0, v0.x);
                m1 = fmaxf(m1, v0.y);
            }
        }

        // w-pool: 8 lanes per pw bin gather absolute columns x+w via shuffle.
        // All lanes participate (shuffles must be unconditional).
        float r = -INFINITY;
        #pragma unroll
        for (int k = 0; k < 3; ++k) {
            const int w  = ws + j + k * 8;
            const int wa = x + w;                   // absolute column, < 128
            const float a = __shfl(m0, (wa >> 1) & 63, 64);
            const float b = __shfl(m1, (wa >> 1) & 63, 64);
            if (w < we) r = fmaxf(r, (wa & 1) ? b : a);
        }
        r = fmaxf(r, __shfl_xor(r, 8, 64));
        r = fmaxf(r, __shfl_xor(r, 16, 64));
        r = fmaxf(r, __shfl_xor(r, 32, 64));
        // after the xor tree every lane holds the result for (ph, pw=lane&7)

        if ((lane >> 3) == ph) keep = r;
    }

    // One fully-coalesced store per (n, c): element lane = (ph=lane>>3, pw=lane&7).
    out[((size_t)n * C_ + c) * (PH_ * PW_) + lane] = keep;
}

extern "C" void kernel_launch(void* const* d_in, const int* in_sizes, int n_in,
                              void* d_out, int out_size, void* d_ws, size_t ws_size,
                              hipStream_t stream) {
    const float* fm   = (const float*)d_in[0];
    const int*   rois = (const int*)d_in[1];
    float*       out  = (float*)d_out;
    const int N = in_sizes[1] / 4;

    dim3 grid(64 * N);   // 8 xcd * 8 csub * N
    roi_pool_kernel<<<grid, 256, 0, stream>>>(fm, rois, out, N);
}

// Round 5
// 161.433 us; speedup vs baseline: 1.3145x; 1.3145x over previous
//
#include <hip/hip_runtime.h>
#include <math.h>

// Problem constants: C=256, H=W=128, PH=PW=8.
#define C_ 256
#define H_ 128
#define W_ 128
#define PH_ 8
#define PW_ 8
#define HW_ (H_ * W_)

__device__ __forceinline__ float4 max4(float4 a, float4 b) {
    return make_float4(fmaxf(a.x, b.x), fmaxf(a.y, b.y),
                       fmaxf(a.z, b.z), fmaxf(a.w, b.w));
}

// ---------- Kernel 1: transpose (C, H*W) -> (H*W, C), XCD-affine ----------
// Tile = 32 channels x 256 positions. bid&7 = channel-group g -> runs on XCD g
// (dispatch round-robin), so fmt's slice for group g is produced in XCD g's L2,
// exactly where pool_kernel (also bid&7 = g) consumes it.
// LDS: stride 257 + lane-swizzled quad offsets -> <=2-way conflicts (free).
__global__ __launch_bounds__(256) void transpose_kernel(
    const float* __restrict__ fm, float* __restrict__ fmt)
{
    __shared__ float tile[32 * 257];
    const int tid = threadIdx.x;
    const int g   = blockIdx.x & 7;          // channel group -> XCD
    const int hwb = blockIdx.x >> 3;
    const int c0  = g * 32;
    const int hw0 = hwb * 256;

    // Read: wave-uniform channel row, 64 lanes x float4 = 1 KB contiguous.
    const int l    = tid & 63;
    const int crow = tid >> 6;               // 0..3
    const int sw   = (l >> 3) & 3;           // lane-dependent quad swizzle
    #pragma unroll
    for (int k = 0; k < 8; ++k) {
        const int c = crow + 4 * k;          // 0..31
        const float4 v = *(const float4*)(fm + (size_t)(c0 + c) * HW_ + hw0 + 4 * l);
        float* t = tile + c * 257 + 4 * l;
        // element hw=4l+i stored at quad offset (i+sw)&3
        t[(0 + sw) & 3] = v.x;
        t[(1 + sw) & 3] = v.y;
        t[(2 + sw) & 3] = v.z;
        t[(3 + sw) & 3] = v.w;
    }
    __syncthreads();

    // Write: lanes = 8 channel-quads x 8 hw rows; 128 B contiguous per hw row.
    const int cq  = tid & 7;
    const int hwr = tid >> 3;                // 0..31
    #pragma unroll
    for (int m = 0; m < 8; ++m) {
        const int hw = hwr + 32 * m;
        // stored offset of (c, hw): (hw&~3) | (((hw&3) + (hw>>5)) & 3)
        const int o  = (hw & ~3) | (((hw & 3) + m) & 3);
        float4 w;
        w.x = tile[(4 * cq + 0) * 257 + o];
        w.y = tile[(4 * cq + 1) * 257 + o];
        w.z = tile[(4 * cq + 2) * 257 + o];
        w.w = tile[(4 * cq + 3) * 257 + o];
        *(float4*)(fmt + (size_t)(hw0 + hw) * C_ + c0 + 4 * cq) = w;
    }
}

// ---------- Kernel 2: pooling, channel-major, h-inner loops ----------
// Wave = (n, ph, pw, cg). Lane = 8 position-groups x 8 channel-quads (float4).
// w-steps specialized on nfull (wave-uniform): 0/1/2 extra full steps ->
// 2..6 independent 1KB dwordx4 loads in flight per h iteration.
__global__ __launch_bounds__(256) void pool_kernel(
    const float* __restrict__ fmt, const int* __restrict__ rois,
    float* __restrict__ out, int N)
{
    const int bid = blockIdx.x;
    const int cg  = bid & 7;                 // XCD-affine channel group
    const int m   = bid >> 3;
    const int pq  = m & 1;
    const int ph  = (m >> 1) & 7;
    const int n   = m >> 4;

    const int wid  = threadIdx.x >> 6;
    const int lane = threadIdx.x & 63;
    const int pw   = pq * 4 + wid;           // wave-uniform
    const int pg   = lane >> 3;              // position group 0..7
    const int c    = (cg << 5) + ((lane & 7) << 2);

    const int4 roi = ((const int4*)rois)[n];
    const int y = roi.x, x = roi.y, rH = roi.z, rW = roi.w;

    const int hs = (ph * rH) >> 3;
    const int he = ((ph + 1) * rH + 7) >> 3;
    const int nrows = he - hs;               // wave-uniform, 1..17
    const int ws = (pw * rW) >> 3;
    const int we = ((pw + 1) * rW + 7) >> 3;
    const int bw = we - ws;                  // 1..17
    const int nfull = (bw - 1) >> 3;         // 0, 1, or 2 (wave-uniform)
    const int wlast = (bw >= 8) ? (we - 8 + pg) : (ws + min(pg, bw - 1));

    const float* rowbase = fmt + ((size_t)(y + hs) * W_ + x) * C_ + c;
    const size_t HSF = (size_t)W_ * C_;      // h stride in floats

    float4 acc = make_float4(-INFINITY, -INFINITY, -INFINITY, -INFINITY);

    if (nfull == 0) {
        const float* p = rowbase + (size_t)wlast * C_;
        int cnt = nrows;
        while (cnt >= 4) {
            const float4 a = *(const float4*)(p);
            const float4 b = *(const float4*)(p + HSF);
            const float4 d = *(const float4*)(p + 2 * HSF);
            const float4 e = *(const float4*)(p + 3 * HSF);
            p += 4 * HSF; cnt -= 4;
            acc = max4(acc, max4(max4(a, b), max4(d, e)));
        }
        while (cnt > 0) {
            const float4 a = *(const float4*)(p);
            p += HSF; --cnt;
            acc = max4(acc, a);
        }
    } else if (nfull == 1) {
        const float* p0 = rowbase + (size_t)(ws + pg) * C_;
        const float* p1 = rowbase + (size_t)wlast * C_;
        int cnt = nrows;
        while (cnt >= 2) {
            const float4 a0 = *(const float4*)(p0);
            const float4 a1 = *(const float4*)(p1);
            const float4 b0 = *(const float4*)(p0 + HSF);
            const float4 b1 = *(const float4*)(p1 + HSF);
            p0 += 2 * HSF; p1 += 2 * HSF; cnt -= 2;
            acc = max4(acc, max4(max4(a0, a1), max4(b0, b1)));
        }
        if (cnt) {
            const float4 a0 = *(const float4*)(p0);
            const float4 a1 = *(const float4*)(p1);
            acc = max4(acc, max4(a0, a1));
        }
    } else {
        const float* p0 = rowbase + (size_t)(ws + pg) * C_;
        const float* p1 = p0 + 8 * C_;
        const float* p2 = rowbase + (size_t)wlast * C_;
        int cnt = nrows;
        while (cnt >= 2) {
            const float4 a0 = *(const float4*)(p0);
            const float4 a1 = *(const float4*)(p1);
            const float4 a2 = *(const float4*)(p2);
            const float4 b0 = *(const float4*)(p0 + HSF);
            const float4 b1 = *(const float4*)(p1 + HSF);
            const float4 b2 = *(const float4*)(p2 + HSF);
            p0 += 2 * HSF; p1 += 2 * HSF; p2 += 2 * HSF; cnt -= 2;
            acc = max4(acc, max4(max4(max4(a0, a1), max4(a2, b0)),
                                 max4(b1, b2)));
        }
        if (cnt) {
            const float4 a0 = *(const float4*)(p0);
            const float4 a1 = *(const float4*)(p1);
            const float4 a2 = *(const float4*)(p2);
            acc = max4(acc, max4(max4(a0, a1), a2));
        }
    }

    // reduce across the 8 position groups (fixed xor swizzles, conflict-free)
    #pragma unroll
    for (int mask = 8; mask <= 32; mask <<= 1) {
        acc.x = fmaxf(acc.x, __shfl_xor(acc.x, mask, 64));
        acc.y = fmaxf(acc.y, __shfl_xor(acc.y, mask, 64));
        acc.z = fmaxf(acc.z, __shfl_xor(acc.z, mask, 64));
        acc.w = fmaxf(acc.w, __shfl_xor(acc.w, mask, 64));
    }

    if (lane < 8) {
        float* o = out + ((size_t)n * C_ + c) * (PH_ * PW_) + ph * PW_ + pw;
        o[0]                   = acc.x;
        o[PH_ * PW_]           = acc.y;
        o[2 * (PH_ * PW_)]     = acc.z;
        o[3 * (PH_ * PW_)]     = acc.w;
    }
}

// ---------- Fallback (R1 kernel) if ws is too small for the transpose ----------
__global__ __launch_bounds__(256) void roi_pool_fallback(
    const float* __restrict__ fm, const int* __restrict__ rois,
    float* __restrict__ out, int N)
{
    const int wid  = threadIdx.x >> 6;
    const int lane = threadIdx.x & 63;
    const int bid  = blockIdx.x;
    const int xcd  = bid & 7;
    const int t    = bid >> 3;
    const int csub = t & 7;
    const int n    = t >> 3;
    if (n >= N) return;
    const int c = (xcd << 5) + (csub << 2) + wid;

    const int4 roi = ((const int4*)rois)[n];
    const int y = roi.x, x = roi.y, rH = roi.z, rW = roi.w;

    const float2* plane2 = (const float2*)(fm + (size_t)c * (H_ * W_));
    const int pw = lane & 7;
    const int j  = lane >> 3;
    const int ws = (pw * rW) >> 3;
    const int we = (((pw + 1) * rW) + 7) >> 3;

    #pragma unroll
    for (int ph = 0; ph < PH_; ++ph) {
        const int hs = (ph * rH) >> 3;
        const int he = ((ph + 1) * rH + 7) >> 3;
        const float2* p = plane2 + (size_t)(y + hs) * (W_ / 2) + lane;
        float m0 = -INFINITY, m1 = -INFINITY;
        int cnt = he - hs;
        while (cnt >= 2) {
            const float2 a = p[0];
            const float2 b = p[W_ / 2];
            p += W_; cnt -= 2;
            m0 = fmaxf(m0, fmaxf(a.x, b.x));
            m1 = fmaxf(m1, fmaxf(a.y, b.y));
        }
        if (cnt) { const float2 a = p[0]; m0 = fmaxf(m0, a.x); m1 = fmaxf(m1, a.y); }

        float r = -INFINITY;
        #pragma unroll
        for (int k = 0; k < 3; ++k) {
            const int w  = ws + j + k * 8;
            const int wa = x + w;
            const float a = __shfl(m0, (wa >> 1) & 63, 64);
            const float b = __shfl(m1, (wa >> 1) & 63, 64);
            if (w < we) r = fmaxf(r, (wa & 1) ? b : a);
        }
        r = fmaxf(r, __shfl_xor(r, 8, 64));
        r = fmaxf(r, __shfl_xor(r, 16, 64));
        r = fmaxf(r, __shfl_xor(r, 32, 64));
        if (lane < PW_) out[(((size_t)n * C_ + c) * PH_ + ph) * PW_ + lane] = r;
    }
}

extern "C" void kernel_launch(void* const* d_in, const int* in_sizes, int n_in,
                              void* d_out, int out_size, void* d_ws, size_t ws_size,
                              hipStream_t stream) {
    const float* fm   = (const float*)d_in[0];
    const int*   rois = (const int*)d_in[1];
    float*       out  = (float*)d_out;
    const int N = in_sizes[1] / 4;

    const size_t need = (size_t)HW_ * C_ * sizeof(float);
    if (ws_size >= need) {
        float* fmt = (float*)d_ws;
        transpose_kernel<<<dim3((HW_ / 256) * 8), 256, 0, stream>>>(fm, fmt);
        pool_kernel<<<dim3(N * 128), 256, 0, stream>>>(fmt, rois, out, N);
    } else {
        roi_pool_fallback<<<dim3(64 * N), 256, 0, stream>>>(fm, rois, out, N);
    }
}